// Round 7
// baseline (208.234 us; speedup 1.0000x reference)
//
#include <hip/hip_runtime.h>

// YOLO loss: N=4096, S=14, B=2, NCLS=20.  Cells = 4096*14*14 = 802816.
//
// v8: v7's wave-autonomous coalesced staging, with measured-good width-16 DMA.
//  - v7 post-mortem: global_load_lds width=12 is the only untested-semantics
//    ingredient (guide-measured widths: 4 and 16). A 16-vs-12 LDS lane-stride
//    mismatch scrambles the slab -> sqrtf(garbage) -> NaN. Hypothesis unrun.
//  - Structure: each wave stages its own 64-cell pred slab (7680 B) via 8 full
//    width-16 DMA instrs (8192 B): the 512 B overrun writes the NEXT wave's
//    first 512 B with IDENTICAL data (same global bytes; duplicate same-value
//    LDS writes are race-benign) -- no partial-wave exec, no barrier. Wave 3
//    overruns into a 512 B slack tail. The grid's last 32 lanes would read
//    past pred's end -> per-lane clamp, clamped data lands in never-read slack.
//  - No __syncthreads anywhere: each wave drains only its own vmcnt and
//    proceeds; waves de-synchronize so DMA overlaps compute chip-wide.
//    LDS 31232 B -> 5 blocks/CU = 20 waves/CU (62%), vs v5's 12.
//  - tcls stays direct (80 B-stride float4: 400 line-touches/wave, the mild
//    offender) to dodge the 200 B/cell LDS trap that capped v5 at 3 blocks/CU.
//  - Atomics: per-wave, 4 RMWs from lane 0, spread over 64 cache lines
//    (12544 RMWs, ~196/line, parallel across TCC slices, ~1 us hidden).
//  - Per-cell math bit-identical to v1..v6 (all passed, absmax 0).

#define NCELLS (4096 * 14 * 14)
#define NBLOCKS (NCELLS / 256)   // 3136, exact
#define NLINES 64                // partial-sum cache lines (64 x 64B = 4KB)

// ws layout (floats): lines j=0..63: ws[16j+k], k=0..3 = cls,noobj,contain,reg
// partials for waves with (gwid&63)==j.  int at float-index 1024 = mask flag.

typedef const __attribute__((address_space(1))) void* gas_t;
typedef __attribute__((address_space(3))) void* las_t;

__device__ __forceinline__ void gload_lds16(const void* g, void* l) {
    // per-lane global src; wave-uniform LDS dst (HW adds lane*16)
    __builtin_amdgcn_global_load_lds((gas_t)g, (las_t)l, 16, 0, 0);
}

__global__ void yolo_zero_kernel(float* __restrict__ ws) {
    const int t = threadIdx.x;   // 256 threads
#pragma unroll
    for (int i = 0; i < 5; ++i) {
        const int k = t + 256 * i;
        if (k < 1040) ws[k] = 0.0f;   // 64 lines + flag line
    }
}

// Detect whether the mask buffer is int32 (bytes 4k+1..4k+3 all zero) or
// 1-byte bool (random nonzero bytes at non-multiple-of-4 offsets).
__global__ void yolo_detect_kernel(const unsigned char* __restrict__ mb,
                                   int* __restrict__ flag) {
    int t = threadIdx.x;
    unsigned int found = 0;
#pragma unroll
    for (int k = 0; k < 16; ++k) {
        int slot = t * 16 + k;
        found |= mb[4 * slot + 1] | mb[4 * slot + 2] | mb[4 * slot + 3];
    }
    if (found) atomicOr(flag, 1);  // 1 => bool8 layout
}

__global__ __launch_bounds__(256) void yolo_main_kernel(
    const float* __restrict__ pred,
    const float* __restrict__ tbox,
    const float* __restrict__ tcls,
    const void* __restrict__ mask,
    const int* __restrict__ flag,
    float* __restrict__ ws) {
    __shared__ float sp[256 * 30 + 128];   // 4 wave slabs of 7680 B + 512 B slack

    const int t = threadIdx.x;
    const int lane = t & 63;
    const int wid = t >> 6;
    const int c = blockIdx.x * 256 + t;  // this thread's cell

    // ---- stage this wave's 64-cell pred slab: 8 x 1024B width-16 DMA ----
    {
        const char* gbase =
            (const char*)pred + (long long)(blockIdx.x * 256 + wid * 64) * 120;
        const char* gend = (const char*)pred + (long long)NCELLS * 120;
        char* lbase = (char*)sp + wid * 7680;
#pragma unroll
        for (int k = 0; k < 8; ++k) {
            const char* src = gbase + k * 1024 + lane * 16;
            if (src + 16 > gend) src = gend - 16;  // only the grid's last 32 lanes
            gload_lds16(src, lbase + k * 1024);
        }
    }

    // ---- direct register loads (overlap the in-flight DMA) ----
    float tc[20];
    {
        const float4* c4 = (const float4*)(tcls + (long long)20 * c);
#pragma unroll
        for (int k = 0; k < 5; ++k) {
            float4 v = c4[k];
            tc[4 * k] = v.x;
            tc[4 * k + 1] = v.y;
            tc[4 * k + 2] = v.z;
            tc[4 * k + 3] = v.w;
        }
    }
    const float4 tb = *(const float4*)(tbox + (long long)4 * c);
    const int mode = *flag;  // uniform across grid
    float m;
    if (mode) {
        m = ((const unsigned char*)mask)[c] ? 1.0f : 0.0f;
    } else {
        m = ((const int*)mask)[c] ? 1.0f : 0.0f;
    }

    // drain this wave's loads (DMA + register); no block barrier anywhere
    asm volatile("s_waitcnt vmcnt(0)" ::: "memory");
    __builtin_amdgcn_sched_barrier(0);   // rule #18: pin nothing above the wait

    const float* pc = sp + wid * 1920 + 30 * lane;  // this cell's 30 pred floats

    // ---- per-cell losses (bit-identical to v1..v6) ----
    float s = 0.0f;
#pragma unroll
    for (int i = 0; i < 20; ++i) {
        float d = pc[10 + i] - tc[i];
        s += d * d;
    }
    float cls_s = m * s;

    float pv[10];
#pragma unroll
    for (int i = 0; i < 10; ++i) pv[i] = pc[i];

    float conf0 = pv[4], conf1 = pv[9];
    float noobj_s = (1.0f - m) * (conf0 * conf0 + conf1 * conf1);

    float iou[2];
    float at = (tb.z - tb.x) * (tb.w - tb.y);
#pragma unroll
    for (int b = 0; b < 2; ++b) {
        int base = 5 * b;
        float x = pv[base] / 14.0f;
        float y = pv[base + 1] / 14.0f;
        float w = pv[base + 2];
        float h = pv[base + 3];
        float p1x = x - w * 0.5f, p1y = y - h * 0.5f;
        float p2x = x + w * 0.5f, p2y = y + h * 0.5f;
        float ltx = fmaxf(p1x, tb.x), lty = fmaxf(p1y, tb.y);
        float rbx = fminf(p2x, tb.z), rby = fminf(p2y, tb.w);
        float iw = fmaxf(rbx - ltx, 0.0f), ih = fmaxf(rby - lty, 0.0f);
        float inter = iw * ih;
        float ap = w * h;
        iou[b] = inter / (ap + at - inter);
    }
    // jnp.argmax: first max wins -> pick box1 only if strictly greater
    int best = (iou[1] > iou[0]) ? 5 : 0;
    float bx = pv[best], by = pv[best + 1], bw = pv[best + 2], bh = pv[best + 3],
          bc = pv[best + 4];

    float contain_s = m * (bc - 1.0f) * (bc - 1.0f);

    float dx = bx - tb.x, dy = by - tb.y;
    float dw = sqrtf(bw) - sqrtf(tb.z);
    float dh = sqrtf(bh) - sqrtf(tb.w);
    float reg_s = m * (dx * dx + dy * dy + dw * dw + dh * dh);

    // ---- per-wave reduction: shuffle -> 4 atomics from lane 0 ----
#pragma unroll
    for (int off = 32; off > 0; off >>= 1) {
        cls_s += __shfl_down(cls_s, off, 64);
        noobj_s += __shfl_down(noobj_s, off, 64);
        contain_s += __shfl_down(contain_s, off, 64);
        reg_s += __shfl_down(reg_s, off, 64);
    }
    if (lane == 0) {
        const int line = 16 * (((blockIdx.x << 2) | wid) & (NLINES - 1));
        atomicAdd(&ws[line + 0], cls_s);
        atomicAdd(&ws[line + 1], noobj_s);
        atomicAdd(&ws[line + 2], contain_s);
        atomicAdd(&ws[line + 3], reg_s);
    }
}

__global__ void yolo_final_kernel(const float* __restrict__ ws,
                                  float* __restrict__ out) {
    const int t = threadIdx.x;   // 64 threads, one partial line each
    float4 v = ((const float4*)ws)[4 * t];   // line t: ws[16t .. 16t+3]
#pragma unroll
    for (int off = 32; off > 0; off >>= 1) {
        v.x += __shfl_down(v.x, off, 64);
        v.y += __shfl_down(v.y, off, 64);
        v.z += __shfl_down(v.z, off, 64);
        v.w += __shfl_down(v.w, off, 64);
    }
    if (t == 0) {
        const float inv_n = 1.0f / 4096.0f;
        const float cls = v.x * inv_n;
        const float noobj = v.y * inv_n;
        const float contain = v.z * inv_n;
        const float reg = v.w * inv_n;
        out[0] = cls + 0.5f * noobj + 5.0f * reg + contain;
        out[1] = reg;
        out[2] = contain;
        out[3] = noobj;
        out[4] = cls;
    }
}

extern "C" void kernel_launch(void* const* d_in, const int* in_sizes, int n_in,
                              void* d_out, int out_size, void* d_ws,
                              size_t ws_size, hipStream_t stream) {
    const float* pred = (const float*)d_in[0];
    const float* tbox = (const float*)d_in[1];
    const float* tcls = (const float*)d_in[2];
    const void* mask = d_in[3];
    float* ws = (float*)d_ws;
    float* out = (float*)d_out;

    yolo_zero_kernel<<<1, 256, 0, stream>>>(ws);
    yolo_detect_kernel<<<1, 256, 0, stream>>>((const unsigned char*)mask,
                                              (int*)(ws + 1024));
    yolo_main_kernel<<<NBLOCKS, 256, 0, stream>>>(pred, tbox, tcls, mask,
                                                  (const int*)(ws + 1024), ws);
    yolo_final_kernel<<<1, 64, 0, stream>>>(ws, out);
}